// Round 5
// baseline (184.796 us; speedup 1.0000x reference)
//
#include <hip/hip_runtime.h>
#include <hip/hip_bf16.h>
#include <stdint.h>

// Problem constants
#define M_TOK 2048   // B*S
#define N_OUT 4096   // OUT_F
#define K_IN  4096   // IN_F
#define GROUPSZ 128
#define NGRP  32

typedef signed char i8;
typedef int    intx4  __attribute__((ext_vector_type(4)));
typedef float  floatx4 __attribute__((ext_vector_type(4)));

#define AS1 __attribute__((address_space(1)))
#define AS3 __attribute__((address_space(3)))

// ---------------- Kernel 1: fused quantization pass (one dispatch).
#define XQ_BLOCKS (M_TOK)                       // 2048, 256 thr = 1 row
#define WQ_BLOCKS (N_OUT * K_IN / 16 / 256)     // 4096

__global__ __launch_bounds__(256) void quant_kernel(
    const float* __restrict__ x, const int* __restrict__ wq,
    i8* __restrict__ xq, i8* __restrict__ wq8, float* __restrict__ sx) {
  __shared__ float red[4];
  int b = blockIdx.x;
  int tid = threadIdx.x;
  if (b < XQ_BLOCKS) {
    const float* xr = x + (size_t)b * K_IN;
    int e0 = tid * 16;
    float4 v0 = *(const float4*)(xr + e0);
    float4 v1 = *(const float4*)(xr + e0 + 4);
    float4 v2 = *(const float4*)(xr + e0 + 8);
    float4 v3 = *(const float4*)(xr + e0 + 12);
    float m = fabsf(v0.x);
    m = fmaxf(m, fabsf(v0.y)); m = fmaxf(m, fabsf(v0.z)); m = fmaxf(m, fabsf(v0.w));
    m = fmaxf(m, fabsf(v1.x)); m = fmaxf(m, fabsf(v1.y)); m = fmaxf(m, fabsf(v1.z)); m = fmaxf(m, fabsf(v1.w));
    m = fmaxf(m, fabsf(v2.x)); m = fmaxf(m, fabsf(v2.y)); m = fmaxf(m, fabsf(v2.z)); m = fmaxf(m, fabsf(v2.w));
    m = fmaxf(m, fabsf(v3.x)); m = fmaxf(m, fabsf(v3.y)); m = fmaxf(m, fabsf(v3.z)); m = fmaxf(m, fabsf(v3.w));
#pragma unroll
    for (int off = 32; off > 0; off >>= 1)
      m = fmaxf(m, __shfl_xor(m, off, 64));
    int lane = tid & 63, wv = tid >> 6;
    if (lane == 0) red[wv] = m;
    __syncthreads();
    m = fmaxf(fmaxf(red[0], red[1]), fmaxf(red[2], red[3]));
    float inv = (m > 0.f) ? 127.f / m : 0.f;
    union { i8 q[16]; int4 v; } u;
    u.q[0]  = (i8)(int)rintf(v0.x * inv); u.q[1]  = (i8)(int)rintf(v0.y * inv);
    u.q[2]  = (i8)(int)rintf(v0.z * inv); u.q[3]  = (i8)(int)rintf(v0.w * inv);
    u.q[4]  = (i8)(int)rintf(v1.x * inv); u.q[5]  = (i8)(int)rintf(v1.y * inv);
    u.q[6]  = (i8)(int)rintf(v1.z * inv); u.q[7]  = (i8)(int)rintf(v1.w * inv);
    u.q[8]  = (i8)(int)rintf(v2.x * inv); u.q[9]  = (i8)(int)rintf(v2.y * inv);
    u.q[10] = (i8)(int)rintf(v2.z * inv); u.q[11] = (i8)(int)rintf(v2.w * inv);
    u.q[12] = (i8)(int)rintf(v3.x * inv); u.q[13] = (i8)(int)rintf(v3.y * inv);
    u.q[14] = (i8)(int)rintf(v3.z * inv); u.q[15] = (i8)(int)rintf(v3.w * inv);
    *(int4*)(xq + (size_t)b * K_IN + e0) = u.v;
    if (tid == 0) sx[b] = m * (1.f / 127.f);
  } else {
    size_t t = (size_t)(b - XQ_BLOCKS) * 256 + tid;   // 1M threads
    size_t base = t * 16;
    const int* src = wq + base;
    int4 a0 = *(const int4*)(src);
    int4 a1 = *(const int4*)(src + 4);
    int4 a2 = *(const int4*)(src + 8);
    int4 a3 = *(const int4*)(src + 12);
    union { i8 q[16]; int4 v; } u;
    u.q[0]  = (i8)a0.x; u.q[1]  = (i8)a0.y; u.q[2]  = (i8)a0.z; u.q[3]  = (i8)a0.w;
    u.q[4]  = (i8)a1.x; u.q[5]  = (i8)a1.y; u.q[6]  = (i8)a1.z; u.q[7]  = (i8)a1.w;
    u.q[8]  = (i8)a2.x; u.q[9]  = (i8)a2.y; u.q[10] = (i8)a2.z; u.q[11] = (i8)a2.w;
    u.q[12] = (i8)a3.x; u.q[13] = (i8)a3.y; u.q[14] = (i8)a3.z; u.q[15] = (i8)a3.w;
    *(int4*)(wq8 + base) = u.v;
  }
}

// ---------------- Kernel 2: int8 GEMM, 8-phase-style pipelined schedule.
// R12 (post-mortem R11: conflicts=0 but DS/MFMA/VALU pipes SERIALIZE —
// their cycle sums equal the measured step time; 4-wave blocks convoy).
// Port of the m201 phase template:
//  - BM=128 x BN=256 x BK=128, 512 thr = 8 waves (2M x 4N), wave 64x64.
//    Grid (16,16)=256 = 1 block/CU. LDS: A 2x16K + B 2x32K + sws 32K = 128KB.
//  - 4 phases per K-tile (j-pair x k-half). Each phase:
//    {ds_read subtile || issue gload_lds -> barrier -> lgkm(0) ->
//     setprio(1) 8xMFMA setprio(0) [-> rescale] -> barrier}.
//  - Staging spread: P0 issues B1(t+1), P1 B2(t+1), P2 A(t+2) (A-region of
//    buf cur is read-complete at P1-end barrier). One counted vmcnt(2) per
//    tile at P3 (t+1's 6 loads done; A(t+2) pair stays in flight). Never
//    drains to 0 in-loop.
//  - Verified pieces carried: 128B-row 3-bit XOR swizzle (0 conflicts),
//    magic-bias rescale (exact; |dot|<=113792 << 2^22), mfma_i32_16x16x64.
#define BM 128
#define BN 256
#define BK 128
#define NT (K_IN / BK)   // 32

__global__ __launch_bounds__(512, 2) void gemm_i8_kernel(
    const i8* __restrict__ Aq, const i8* __restrict__ Bq,
    const float* __restrict__ sx, const float* __restrict__ sw,
    const float* __restrict__ bias, float* __restrict__ C) {
  __shared__ i8 As[2 * BM * BK];        // 32 KB (double-buffered)
  __shared__ i8 Bs[2 * BN * BK];        // 64 KB (double-buffered)
  __shared__ float sws[NGRP * BN];      // 32 KB: s_w[g][rowB0 + c]

  const int tid  = threadIdx.x;
  const int lane = tid & 63;
  const int wave = tid >> 6;       // 0..7
  const int quad = lane >> 4;      // 0..3
  const int l16  = lane & 15;
  const int bm = blockIdx.y;
  const int bn = blockIdx.x;
  const int wm = wave >> 2;        // 0..1 -> 64-row slab of 128
  const int wn = wave & 3;         // 0..3 -> 64-col slab of 256

  const int rowA0 = bm * BM;
  const int rowB0 = bn * BN;

  // Staging sources (hoisted). A: 1024 chunks (2 loads/thr); B: 2048 (4).
  // Global chunk-col pre-swizzled (involution c ^= row&7); LDS linear.
  const i8* srcA[2]; const i8* srcB[4];
#pragma unroll
  for (int i = 0; i < 2; ++i) {
    int chunk = i * 512 + tid;
    int row = chunk >> 3;                   // 0..127
    int csw = (chunk & 7) ^ (row & 7);
    srcA[i] = Aq + (size_t)(rowA0 + row) * K_IN + (csw << 4);
  }
#pragma unroll
  for (int i = 0; i < 4; ++i) {
    int chunk = i * 512 + tid;
    int row = chunk >> 3;                   // 0..255
    int csw = (chunk & 7) ^ (row & 7);
    srcB[i] = Bq + (size_t)(rowB0 + row) * K_IN + (csw << 4);
  }

  auto stageA = [&](int buf, int t) {       // 16 KB: 2 loads/thread
    const size_t ko = (size_t)t * BK;
#pragma unroll
    for (int i = 0; i < 2; ++i)
      __builtin_amdgcn_global_load_lds(
          (const AS1 void*)(srcA[i] + ko),
          (AS3 void*)(As + (size_t)buf * (BM * BK) + (size_t)(i * 512 + wave * 64) * 16),
          16, 0, 0);
  };
  auto stageB1 = [&](int buf, int t) {      // first 16 KB of B-tile
    const size_t ko = (size_t)t * BK;
#pragma unroll
    for (int i = 0; i < 2; ++i)
      __builtin_amdgcn_global_load_lds(
          (const AS1 void*)(srcB[i] + ko),
          (AS3 void*)(Bs + (size_t)buf * (BN * BK) + (size_t)(i * 512 + wave * 64) * 16),
          16, 0, 0);
  };
  auto stageB2 = [&](int buf, int t) {      // second 16 KB of B-tile
    const size_t ko = (size_t)t * BK;
#pragma unroll
    for (int i = 2; i < 4; ++i)
      __builtin_amdgcn_global_load_lds(
          (const AS1 void*)(srcB[i] + ko),
          (AS3 void*)(Bs + (size_t)buf * (BN * BK) + (size_t)(i * 512 + wave * 64) * 16),
          16, 0, 0);
  };

  // Prologue: tile0 (6 loads) + A(1) (2 loads) + sws staging; full drain once.
  stageA(0, 0); stageB1(0, 0); stageB2(0, 0);
  stageA(1, 1);
  {
    int g = tid >> 4, c0 = (tid & 15) * 16;    // 512 thr x 16 floats = 8192
    const float* src = sw + (size_t)g * N_OUT + rowB0 + c0;
    float* dst = sws + g * BN + c0;
    *(float4*)(dst)      = *(const float4*)(src);
    *(float4*)(dst + 4)  = *(const float4*)(src + 4);
    *(float4*)(dst + 8)  = *(const float4*)(src + 8);
    *(float4*)(dst + 12) = *(const float4*)(src + 12);
  }
  __syncthreads();   // one-time full drain (tile0 + A1 + sws landed)

  floatx4 master[4][4];
#pragma unroll
  for (int i = 0; i < 4; ++i)
#pragma unroll
    for (int j = 0; j < 4; ++j) master[i][j] = (floatx4)0.0f;

  const intx4 MAGICV = {0x4B400000, 0x4B400000, 0x4B400000, 0x4B400000};
  const float MAGICF = 12582912.0f;        // 1.5 * 2^23

  const int h  = l16 & 7;
  const int x0 = (quad ^ h) << 4;          // swizzled byte offset, k-half 0
  const int x1 = x0 ^ 64;                  // k-half 1 (chunk ^ 4)

  for (int t = 0; t < NT; ++t) {
    const int cur = t & 1;
    const int nxt = cur ^ 1;
    const i8* Ab = As + (size_t)cur * (BM * BK);
    const i8* Bb = Bs + (size_t)cur * (BN * BK);

    intx4 a0[4], a1[4], b01[2][2], b23[2][2];
    intx4 acc01[4][2], acc23[4][2];
    float swv[4];

    // ---------- P0: reads a[*][k0], b0/b1[k0], swv; stage B1(t+1); MFMA k0,j01
#pragma unroll
    for (int i = 0; i < 4; ++i)
      a0[i] = *(const intx4*)(Ab + (size_t)(wm * 64 + i * 16 + l16) * BK + x0);
    b01[0][0] = *(const intx4*)(Bb + (size_t)(wn * 64 +  0 + l16) * BK + x0);
    b01[1][0] = *(const intx4*)(Bb + (size_t)(wn * 64 + 16 + l16) * BK + x0);
#pragma unroll
    for (int j = 0; j < 4; ++j)
      swv[j] = sws[t * BN + wn * 64 + j * 16 + l16];
    if (t + 1 < NT) stageB1(nxt, t + 1);
    __builtin_amdgcn_s_barrier();
    asm volatile("s_waitcnt lgkmcnt(0)" ::: "memory");
    __builtin_amdgcn_s_setprio(1);
#pragma unroll
    for (int i = 0; i < 4; ++i)
#pragma unroll
      for (int j = 0; j < 2; ++j)
        acc01[i][j] = __builtin_amdgcn_mfma_i32_16x16x64_i8(a0[i], b01[j][0], MAGICV, 0, 0, 0);
    __builtin_amdgcn_s_setprio(0);
    __builtin_amdgcn_s_barrier();

    // ---------- P1: reads a[*][k1], b0/b1[k1]; stage B2(t+1); MFMA k1,j01 + rescale
#pragma unroll
    for (int i = 0; i < 4; ++i)
      a1[i] = *(const intx4*)(Ab + (size_t)(wm * 64 + i * 16 + l16) * BK + x1);
    b01[0][1] = *(const intx4*)(Bb + (size_t)(wn * 64 +  0 + l16) * BK + x1);
    b01[1][1] = *(const intx4*)(Bb + (size_t)(wn * 64 + 16 + l16) * BK + x1);
    if (t + 1 < NT) stageB2(nxt, t + 1);
    __builtin_amdgcn_s_barrier();
    asm volatile("s_waitcnt lgkmcnt(0)" ::: "memory");
    __builtin_amdgcn_s_setprio(1);
#pragma unroll
    for (int i = 0; i < 4; ++i)
#pragma unroll
      for (int j = 0; j < 2; ++j)
        acc01[i][j] = __builtin_amdgcn_mfma_i32_16x16x64_i8(a1[i], b01[j][1], acc01[i][j], 0, 0, 0);
    __builtin_amdgcn_s_setprio(0);
#pragma unroll
    for (int i = 0; i < 4; ++i)
#pragma unroll
      for (int j = 0; j < 2; ++j)
        master[i][j] += (__builtin_bit_cast(floatx4, acc01[i][j]) - MAGICF) * swv[j];
    __builtin_amdgcn_s_barrier();

    // ---------- P2: reads b2/b3[k0]; stage A(t+2) into buf cur (A-region
    // reads of buf cur completed at P1-end barrier); MFMA k0,j23
    b23[0][0] = *(const intx4*)(Bb + (size_t)(wn * 64 + 32 + l16) * BK + x0);
    b23[1][0] = *(const intx4*)(Bb + (size_t)(wn * 64 + 48 + l16) * BK + x0);
    if (t + 2 < NT) stageA(cur, t + 2);
    __builtin_amdgcn_s_barrier();
    asm volatile("s_waitcnt lgkmcnt(0)" ::: "memory");
    __builtin_amdgcn_s_setprio(1);
#pragma unroll
    for (int i = 0; i < 4; ++i)
#pragma unroll
      for (int j = 0; j < 2; ++j)
        acc23[i][j] = __builtin_amdgcn_mfma_i32_16x16x64_i8(a0[i], b23[j][0], MAGICV, 0, 0, 0);
    __builtin_amdgcn_s_setprio(0);
    __builtin_amdgcn_s_barrier();

    // ---------- P3: reads b2/b3[k1]; counted vmcnt (t+1's 6 loads done,
    // A(t+2)'s 2 stay in flight); MFMA k1,j23 + rescale
    b23[0][1] = *(const intx4*)(Bb + (size_t)(wn * 64 + 32 + l16) * BK + x1);
    b23[1][1] = *(const intx4*)(Bb + (size_t)(wn * 64 + 48 + l16) * BK + x1);
    if (t + 1 < NT) {
      if (t + 2 < NT) { asm volatile("s_waitcnt vmcnt(2)" ::: "memory"); }
      else            { asm volatile("s_waitcnt vmcnt(0)" ::: "memory"); }
    }
    __builtin_amdgcn_s_barrier();
    asm volatile("s_waitcnt lgkmcnt(0)" ::: "memory");
    __builtin_amdgcn_s_setprio(1);
#pragma unroll
    for (int i = 0; i < 4; ++i)
#pragma unroll
      for (int j = 0; j < 2; ++j)
        acc23[i][j] = __builtin_amdgcn_mfma_i32_16x16x64_i8(a1[i], b23[j][1], acc23[i][j], 0, 0, 0);
    __builtin_amdgcn_s_setprio(0);
#pragma unroll
    for (int i = 0; i < 4; ++i)
#pragma unroll
      for (int j = 0; j < 2; ++j)
        master[i][j + 2] += (__builtin_bit_cast(floatx4, acc23[i][j]) - MAGICF) * swv[j + 2];
    __builtin_amdgcn_s_barrier();
  }

  // Epilogue: C/D layout col = lane&15 (n), row = quad*4 + reg (m).
#pragma unroll
  for (int i = 0; i < 4; ++i) {
    float4 sxv = *(const float4*)(sx + rowA0 + wm * 64 + i * 16 + quad * 4);
#pragma unroll
    for (int j = 0; j < 4; ++j) {
      int col = rowB0 + wn * 64 + j * 16 + l16;
      float bv = bias[col];
      int rloc = wm * 64 + i * 16 + quad * 4;
      C[(size_t)(rowA0 + rloc + 0) * N_OUT + col] = master[i][j][0] * sxv.x + bv;
      C[(size_t)(rowA0 + rloc + 1) * N_OUT + col] = master[i][j][1] * sxv.y + bv;
      C[(size_t)(rowA0 + rloc + 2) * N_OUT + col] = master[i][j][2] * sxv.z + bv;
      C[(size_t)(rowA0 + rloc + 3) * N_OUT + col] = master[i][j][3] * sxv.w + bv;
    }
  }
}

extern "C" void kernel_launch(void* const* d_in, const int* in_sizes, int n_in,
                              void* d_out, int out_size, void* d_ws, size_t ws_size,
                              hipStream_t stream) {
  const float* x    = (const float*)d_in[0];
  const int*   wq   = (const int*)d_in[1];     // integer input -> int32 per harness
  const float* sw   = (const float*)d_in[2];
  const float* bias = (const float*)d_in[3];
  float* out = (float*)d_out;

  i8*    xq  = (i8*)d_ws;                                          // 8 MB
  i8*    wq8 = (i8*)((char*)d_ws + (size_t)M_TOK * K_IN);          // 16 MB
  float* sx  = (float*)((char*)d_ws + (size_t)M_TOK * K_IN
                                     + (size_t)N_OUT * K_IN);      // 8 KB

  {
    int nblocks = XQ_BLOCKS + WQ_BLOCKS;        // 6144
    quant_kernel<<<nblocks, 256, 0, stream>>>(x, wq, xq, wq8, sx);
  }
  {
    dim3 grid(N_OUT / BN, M_TOK / BM);          // (16, 16) = 256 blocks
    gemm_i8_kernel<<<grid, 512, 0, stream>>>(xq, wq8, sx, sw, bias, out);
  }
}